// Round 1
// baseline (924.975 us; speedup 1.0000x reference)
//
#include <hip/hip_runtime.h>
#include <math.h>

// AFM forward, fp32 correctness-first baseline.
// B=512 batch, F=64 features, K=64 embed, pairs (i<=j) = 2080.
// One block per batch element; 256 threads = 4 waves.
// Wave w handles pairs [w*520, (w+1)*520).

#define BB 512
#define FF 64
#define NPAIRS 2080
#define PPW 520
#define NEG_BIG -3.402823466e38f

__global__ __launch_bounds__(256, 2) void afm_fp32_kernel(
    const float* __restrict__ x,     // [512,64]
    const float* __restrict__ Ww,    // [1,64]
    const float* __restrict__ bw,    // [1]
    const float* __restrict__ cross, // [64,64]
    const float* __restrict__ W1,    // [64,64]
    const float* __restrict__ b1,    // [64]
    const float* __restrict__ w2,    // [64]
    const float* __restrict__ Wd1,   // [32,64]
    const float* __restrict__ bd1,   // [32]
    const float* __restrict__ Wd2,   // [21,32]
    const float* __restrict__ bd2,   // [21]
    const float* __restrict__ Wd3,   // [16,21]
    const float* __restrict__ bd3,   // [16]
    const float* __restrict__ Wo,    // [1,16]
    const float* __restrict__ bo,    // [1]
    float* __restrict__ out)         // [512]
{
    __shared__ float a_s[FF][FF + 1];   // a[i][k] = x_i * cross[i][k], padded
    __shared__ float w1_s[FF][FF + 1];  // W1 staged (row l = output neuron l)
    __shared__ float s_s[NPAIRS];       // scores, then e values
    __shared__ unsigned short lut_s[NPAIRS];
    __shared__ float x_sh[FF];
    __shared__ float red_s[8];
    __shared__ float tmp_s[4][FF];
    __shared__ float mlp_s[FF];
    __shared__ float scal_s[2];         // [0]=m, [1]=denom

    const int tid  = threadIdx.x;
    const int lane = tid & 63;
    const int wave = tid >> 6;
    const int b    = blockIdx.x;

    // ---- stage x row, W1, pair LUT ----
    if (tid < FF) x_sh[tid] = x[b * FF + tid];
    for (int idx = tid; idx < FF * FF; idx += 256)
        w1_s[idx >> 6][idx & 63] = W1[idx];
    if (tid < FF) {
        int i = tid;
        int base = i * FF - (i * (i - 1)) / 2;  // start offset of row i's pairs
        for (int j = i; j < FF; ++j)
            lut_s[base + (j - i)] = (unsigned short)((i << 8) | j);
    }
    __syncthreads();

    // ---- a[i][k] = x_i * cross[i][k] ----
    for (int i = wave; i < FF; i += 4)
        a_s[i][lane] = x_sh[i] * cross[i * FF + lane];

    // ---- each lane holds W1 row 'lane' in registers ----
    float w1r[FF];
    #pragma unroll
    for (int k = 0; k < FF; ++k) w1r[k] = w1_s[lane][k];
    const float b1l = b1[lane];
    const float w2l = w2[lane];
    __syncthreads();

    // ---- pass 1: attention scores ----
    const int pstart = wave * PPW;
    const int pend   = pstart + PPW;
    for (int p = pstart; p < pend; ++p) {
        const int ij = lut_s[p];
        const int i = ij >> 8, j = ij & 255;
        const float v = a_s[i][lane] * a_s[j][lane];
        // h[lane] = b1[lane] + sum_k W1[lane][k] * v[k]  (v broadcast via shfl)
        float h0 = b1l, h1 = 0.f, h2 = 0.f, h3 = 0.f;
        #pragma unroll
        for (int k = 0; k < FF; k += 4) {
            h0 = fmaf(w1r[k + 0], __shfl(v, k + 0, 64), h0);
            h1 = fmaf(w1r[k + 1], __shfl(v, k + 1, 64), h1);
            h2 = fmaf(w1r[k + 2], __shfl(v, k + 2, 64), h2);
            h3 = fmaf(w1r[k + 3], __shfl(v, k + 3, 64), h3);
        }
        float h = (h0 + h1) + (h2 + h3);
        float t = fmaxf(h, 0.f) * w2l;
        #pragma unroll
        for (int off = 32; off > 0; off >>= 1)
            t += __shfl_xor(t, off, 64);
        if (lane == 0) {
            const bool valid = (x_sh[i] != 0.f) && (x_sh[j] != 0.f);
            s_s[p] = valid ? t : NEG_BIG;
        }
    }
    __syncthreads();

    // ---- softmax max (seeded with 0 per reference) ----
    float mx = 0.0f;
    for (int p = tid; p < NPAIRS; p += 256) mx = fmaxf(mx, s_s[p]);
    #pragma unroll
    for (int off = 32; off > 0; off >>= 1)
        mx = fmaxf(mx, __shfl_xor(mx, off, 64));
    if (lane == 0) red_s[wave] = mx;
    __syncthreads();
    if (tid == 0)
        scal_s[0] = fmaxf(fmaxf(red_s[0], red_s[1]), fmaxf(red_s[2], red_s[3]));
    __syncthreads();
    const float m = scal_s[0];

    // ---- e = exp(s - m), denom = exp(-m) + sum e ----
    float sum = 0.f;
    for (int p = tid; p < NPAIRS; p += 256) {
        float e = __expf(s_s[p] - m);   // NEG_BIG - m underflows to 0
        s_s[p] = e;
        sum += e;
    }
    #pragma unroll
    for (int off = 32; off > 0; off >>= 1)
        sum += __shfl_xor(sum, off, 64);
    if (lane == 0) red_s[4 + wave] = sum;
    __syncthreads();
    if (tid == 0)
        scal_s[1] = __expf(-m) + ((red_s[4] + red_s[5]) + (red_s[6] + red_s[7]));
    __syncthreads();
    const float denom = scal_s[1];

    // ---- pass 2: tmp[k] = sum_p e_p * v_p[k] / denom ----
    float acc = 0.f;
    for (int p = pstart; p < pend; ++p) {
        const int ij = lut_s[p];
        const int i = ij >> 8, j = ij & 255;
        acc = fmaf(s_s[p], a_s[i][lane] * a_s[j][lane], acc);
    }
    tmp_s[wave][lane] = acc;
    __syncthreads();
    if (tid < FF)
        mlp_s[tid] = ((tmp_s[0][tid] + tmp_s[1][tid]) +
                      (tmp_s[2][tid] + tmp_s[3][tid])) / denom;
    __syncthreads();

    // ---- deep MLP: 64 -> 32 -> 21 -> 16 -> 1 ----
    float hv = 0.f;
    if (tid < 32) {
        float a1 = bd1[tid];
        for (int k = 0; k < 64; ++k) a1 = fmaf(Wd1[tid * 64 + k], mlp_s[k], a1);
        hv = fmaxf(a1, 0.f);
    }
    __syncthreads();
    if (tid < 32) mlp_s[tid] = hv;
    __syncthreads();
    if (tid < 21) {
        float a2 = bd2[tid];
        for (int k = 0; k < 32; ++k) a2 = fmaf(Wd2[tid * 32 + k], mlp_s[k], a2);
        hv = fmaxf(a2, 0.f);
    }
    __syncthreads();
    if (tid < 21) mlp_s[tid] = hv;
    __syncthreads();
    if (tid < 16) {
        float a3 = bd3[tid];
        for (int k = 0; k < 21; ++k) a3 = fmaf(Wd3[tid * 21 + k], mlp_s[k], a3);
        hv = fmaxf(a3, 0.f);
    }
    __syncthreads();
    if (tid < 16) mlp_s[tid] = hv;
    __syncthreads();

    if (tid == 0) {
        float deep = bo[0];
        for (int k = 0; k < 16; ++k) deep = fmaf(Wo[k], mlp_s[k], deep);
        float lin = bw[0];
        for (int k = 0; k < 64; ++k) lin = fmaf(Ww[k], x_sh[k], lin);
        const float z = lin + deep;
        out[b] = 1.f / (1.f + __expf(-z));
    }
}

extern "C" void kernel_launch(void* const* d_in, const int* in_sizes, int n_in,
                              void* d_out, int out_size, void* d_ws, size_t ws_size,
                              hipStream_t stream) {
    const float* xp    = (const float*)d_in[0];
    const float* Ww    = (const float*)d_in[1];
    const float* bw    = (const float*)d_in[2];
    const float* cross = (const float*)d_in[3];
    const float* W1    = (const float*)d_in[4];
    const float* b1    = (const float*)d_in[5];
    const float* w2    = (const float*)d_in[6];
    const float* Wd1   = (const float*)d_in[7];
    const float* bd1   = (const float*)d_in[8];
    const float* Wd2   = (const float*)d_in[9];
    const float* bd2   = (const float*)d_in[10];
    const float* Wd3   = (const float*)d_in[11];
    const float* bd3   = (const float*)d_in[12];
    const float* Wo    = (const float*)d_in[13];
    const float* bo    = (const float*)d_in[14];
    float* out = (float*)d_out;

    afm_fp32_kernel<<<BB, 256, 0, stream>>>(xp, Ww, bw, cross, W1, b1, w2,
                                            Wd1, bd1, Wd2, bd2, Wd3, bd3,
                                            Wo, bo, out);
}

// Round 2
// 146.496 us; speedup vs baseline: 6.3140x; 6.3140x over previous
//
#include <hip/hip_runtime.h>
#include <math.h>

// AFM forward, round 2: attention-score GEMM via f16 MFMA.
// B=512 blocks (1 per batch row), 512 threads (8 waves).
// Score GEMM: H[l][p] = sum_k W1[l][k] * V[k][p], M=64, K=64, N=2080.
// V generated in f16 tiles of 256 pairs in LDS; A (=W1 f16) resident in VGPRs.
// Softmax / pass-2 / deep-MLP identical in structure to the verified round-1 code.

#define BB 512
#define FF 64
#define NPAIRS 2080
#define THREADS 512
#define CHUNK 256
#define NCHUNK 9          // 8 full chunks of 256 + tail of 32
#define NEG_BIG -3.402823466e38f

typedef _Float16 half8 __attribute__((ext_vector_type(8)));
typedef float f32x4 __attribute__((ext_vector_type(4)));

// XOR swizzle of 16B column groups within a Vt row: kills the 8-way
// bank conflicts a plain [p][k] layout has (row stride 36 words == 4 banks).
__device__ __forceinline__ int vcol(int p, int kg) { return (kg ^ (p & 7)) << 3; }

__global__ __launch_bounds__(THREADS, 4) void afm_mfma_kernel(
    const float* __restrict__ x,     // [512,64]
    const float* __restrict__ Ww,    // [1,64]
    const float* __restrict__ bw,    // [1]
    const float* __restrict__ cross, // [64,64]
    const float* __restrict__ W1,    // [64,64]
    const float* __restrict__ b1,    // [64]
    const float* __restrict__ w2,    // [64]
    const float* __restrict__ Wd1,   // [32,64]
    const float* __restrict__ bd1,   // [32]
    const float* __restrict__ Wd2,   // [21,32]
    const float* __restrict__ bd2,   // [21]
    const float* __restrict__ Wd3,   // [16,21]
    const float* __restrict__ bd3,   // [16]
    const float* __restrict__ Wo,    // [1,16]
    const float* __restrict__ bo,    // [1]
    float* __restrict__ out)         // [512]
{
    __shared__ __align__(16) float     a_s[FF][68];     // stride 68 fp32: 16B-aligned rows
    __shared__ __align__(16) _Float16  w1h_s[FF][72];   // W1 in f16, stride 72
    __shared__ __align__(16) _Float16  Vt[CHUNK][72];   // V^T tile (p-major, k contiguous, swizzled)
    __shared__ float s_s[NPAIRS];
    __shared__ unsigned short lut_s[NPAIRS];
    __shared__ float x_sh[FF];
    __shared__ float b1_s[FF];
    __shared__ float w2_s[FF];
    __shared__ float tmp_s[8][FF];
    __shared__ float mlp_s[FF];
    __shared__ float red_s[16];
    __shared__ float scal_s[2];

    const int tid  = threadIdx.x;
    const int lane = tid & 63;
    const int wave = tid >> 6;
    const int b    = blockIdx.x;
    const int m    = lane & 15;      // MFMA 16-dim index
    const int q    = lane >> 4;      // MFMA quad

    // ---- phase A: stage x, W1(f16), b1, w2 ----
    if (tid < FF) {
        x_sh[tid] = x[b * FF + tid];
        b1_s[tid] = b1[tid];
        w2_s[tid] = w2[tid];
    }
    for (int idx = tid; idx < FF * FF; idx += THREADS)
        w1h_s[idx >> 6][idx & 63] = (_Float16)W1[idx];
    __syncthreads();

    // ---- phase B: a[i][k] = x_i * cross[i][k]; pair LUT with valid bit ----
    for (int i = wave; i < FF; i += 8)
        a_s[i][lane] = x_sh[i] * cross[i * FF + lane];
    if (tid < FF) {
        const int i = tid;
        const int basei = i * FF - (i * (i - 1)) / 2;
        const bool xi = (x_sh[i] != 0.f);
        for (int j = i; j < FF; ++j) {
            const int valid = (xi && (x_sh[j] != 0.f)) ? 0x8000 : 0;
            lut_s[basei + (j - i)] = (unsigned short)((i << 8) | j | valid);
        }
    }
    __syncthreads();

    // ---- A-fragments: W1[m][k], resident for the whole kernel ----
    half8 afr[4][2];
    #pragma unroll
    for (int mt = 0; mt < 4; ++mt)
        #pragma unroll
        for (int kt = 0; kt < 2; ++kt)
            afr[mt][kt] = *(const half8*)&w1h_s[mt * 16 + m][kt * 32 + q * 8];

    // ---- main loop: generate V tile -> MFMA -> scores ----
    for (int c = 0; c < NCHUNK; ++c) {
        const int base   = c * CHUNK;
        const int nPairs = min(CHUNK, NPAIRS - base);
        __syncthreads();   // Vt free from previous chunk's consumers

        // generate: 2 threads per pair (k-halves of 32)
        {
            const int p_local = tid & 255;
            const int k0 = (tid >> 8) * 32;
            if (p_local < nPairs) {
                const int ij = lut_s[base + p_local];
                const int i = (ij >> 8) & 63, j = ij & 63;
                #pragma unroll
                for (int kk = 0; kk < 32; kk += 8) {
                    const float4 ai0 = *(const float4*)&a_s[i][k0 + kk];
                    const float4 ai1 = *(const float4*)&a_s[i][k0 + kk + 4];
                    const float4 aj0 = *(const float4*)&a_s[j][k0 + kk];
                    const float4 aj1 = *(const float4*)&a_s[j][k0 + kk + 4];
                    half8 vv;
                    vv[0] = (_Float16)(ai0.x * aj0.x);
                    vv[1] = (_Float16)(ai0.y * aj0.y);
                    vv[2] = (_Float16)(ai0.z * aj0.z);
                    vv[3] = (_Float16)(ai0.w * aj0.w);
                    vv[4] = (_Float16)(ai1.x * aj1.x);
                    vv[5] = (_Float16)(ai1.y * aj1.y);
                    vv[6] = (_Float16)(ai1.z * aj1.z);
                    vv[7] = (_Float16)(ai1.w * aj1.w);
                    const int kg = (k0 + kk) >> 3;
                    *(half8*)&Vt[p_local][vcol(p_local, kg)] = vv;
                }
            }
        }
        __syncthreads();

        // consume: each wave takes ntile w, w+8, ...
        const int ntiles = nPairs >> 4;
        for (int ntl = wave; ntl < ntiles; ntl += 8) {
            const int prow = ntl * 16 + m;
            f32x4 acc[4];
            #pragma unroll
            for (int mt = 0; mt < 4; ++mt)
                #pragma unroll
                for (int r = 0; r < 4; ++r)
                    acc[mt][r] = b1_s[mt * 16 + q * 4 + r];
            const half8 bfr0 = *(const half8*)&Vt[prow][vcol(prow, 0 * 4 + q)];
            const half8 bfr1 = *(const half8*)&Vt[prow][vcol(prow, 1 * 4 + q)];
            #pragma unroll
            for (int mt = 0; mt < 4; ++mt) {
                acc[mt] = __builtin_amdgcn_mfma_f32_16x16x32_f16(afr[mt][0], bfr0, acc[mt], 0, 0, 0);
                acc[mt] = __builtin_amdgcn_mfma_f32_16x16x32_f16(afr[mt][1], bfr1, acc[mt], 0, 0, 0);
            }
            float sp = 0.f;
            #pragma unroll
            for (int mt = 0; mt < 4; ++mt)
                #pragma unroll
                for (int r = 0; r < 4; ++r)
                    sp = fmaf(w2_s[mt * 16 + q * 4 + r], fmaxf(acc[mt][r], 0.f), sp);
            sp += __shfl_xor(sp, 16, 64);
            sp += __shfl_xor(sp, 32, 64);
            if (lane < 16) {
                const int p = base + ntl * 16 + lane;
                s_s[p] = (lut_s[p] & 0x8000) ? sp : NEG_BIG;
            }
        }
    }
    __syncthreads();

    // ---- softmax (seeded with 0-logit term, exactly as reference) ----
    float mx = 0.0f;
    for (int p = tid; p < NPAIRS; p += THREADS) mx = fmaxf(mx, s_s[p]);
    #pragma unroll
    for (int off = 32; off > 0; off >>= 1)
        mx = fmaxf(mx, __shfl_xor(mx, off, 64));
    if (lane == 0) red_s[wave] = mx;
    __syncthreads();
    if (tid == 0) {
        float mm = red_s[0];
        for (int w = 1; w < 8; ++w) mm = fmaxf(mm, red_s[w]);
        scal_s[0] = mm;
    }
    __syncthreads();
    const float mval = scal_s[0];

    float sum = 0.f;
    for (int p = tid; p < NPAIRS; p += THREADS) {
        const float e = __expf(s_s[p] - mval);   // NEG_BIG underflows to 0
        s_s[p] = e;
        sum += e;
    }
    #pragma unroll
    for (int off = 32; off > 0; off >>= 1)
        sum += __shfl_xor(sum, off, 64);
    if (lane == 0) red_s[8 + wave] = sum;
    __syncthreads();
    if (tid == 0) {
        float ss = __expf(-mval);
        for (int w = 0; w < 8; ++w) ss += red_s[8 + w];
        scal_s[1] = ss;
    }
    __syncthreads();
    const float denom = scal_s[1];

    // ---- pass 2: tmp[k] = sum_p e_p * v_p[k] / denom (fp32, lane = k) ----
    {
        float acc2 = 0.f;
        const int p0 = wave * (NPAIRS / 8), p1 = p0 + (NPAIRS / 8);
        for (int p = p0; p < p1; ++p) {
            const int ij = lut_s[p];
            const int i = (ij >> 8) & 63, j = ij & 63;
            acc2 = fmaf(s_s[p], a_s[i][lane] * a_s[j][lane], acc2);
        }
        tmp_s[wave][lane] = acc2;
    }
    __syncthreads();
    if (tid < FF) {
        float t = 0.f;
        for (int w = 0; w < 8; ++w) t += tmp_s[w][tid];
        mlp_s[tid] = t / denom;
    }
    __syncthreads();

    // ---- deep MLP: 64 -> 32 -> 21 -> 16 -> 1 ----
    float hv = 0.f;
    if (tid < 32) {
        float a1 = bd1[tid];
        for (int k = 0; k < 64; ++k) a1 = fmaf(Wd1[tid * 64 + k], mlp_s[k], a1);
        hv = fmaxf(a1, 0.f);
    }
    __syncthreads();
    if (tid < 32) mlp_s[tid] = hv;
    __syncthreads();
    if (tid < 21) {
        float a2 = bd2[tid];
        for (int k = 0; k < 32; ++k) a2 = fmaf(Wd2[tid * 32 + k], mlp_s[k], a2);
        hv = fmaxf(a2, 0.f);
    }
    __syncthreads();
    if (tid < 21) mlp_s[tid] = hv;
    __syncthreads();
    if (tid < 16) {
        float a3 = bd3[tid];
        for (int k = 0; k < 21; ++k) a3 = fmaf(Wd3[tid * 21 + k], mlp_s[k], a3);
        hv = fmaxf(a3, 0.f);
    }
    __syncthreads();
    if (tid < 16) mlp_s[tid] = hv;
    __syncthreads();

    if (tid == 0) {
        float deep = bo[0];
        for (int k = 0; k < 16; ++k) deep = fmaf(Wo[k], mlp_s[k], deep);
        float lin = bw[0];
        for (int k = 0; k < 64; ++k) lin = fmaf(Ww[k], x_sh[k], lin);
        const float z = lin + deep;
        out[b] = 1.f / (1.f + __expf(-z));
    }
}

extern "C" void kernel_launch(void* const* d_in, const int* in_sizes, int n_in,
                              void* d_out, int out_size, void* d_ws, size_t ws_size,
                              hipStream_t stream) {
    const float* xp    = (const float*)d_in[0];
    const float* Ww    = (const float*)d_in[1];
    const float* bw    = (const float*)d_in[2];
    const float* cross = (const float*)d_in[3];
    const float* W1    = (const float*)d_in[4];
    const float* b1    = (const float*)d_in[5];
    const float* w2    = (const float*)d_in[6];
    const float* Wd1   = (const float*)d_in[7];
    const float* bd1   = (const float*)d_in[8];
    const float* Wd2   = (const float*)d_in[9];
    const float* bd2   = (const float*)d_in[10];
    const float* Wd3   = (const float*)d_in[11];
    const float* bd3   = (const float*)d_in[12];
    const float* Wo    = (const float*)d_in[13];
    const float* bo    = (const float*)d_in[14];
    float* outp = (float*)d_out;

    afm_mfma_kernel<<<BB, THREADS, 0, stream>>>(xp, Ww, bw, cross, W1, b1, w2,
                                                Wd1, bd1, Wd2, bd2, Wd3, bd3,
                                                Wo, bo, outp);
}

// Round 3
// 104.307 us; speedup vs baseline: 8.8678x; 1.4045x over previous
//
#include <hip/hip_runtime.h>
#include <math.h>

// AFM forward, round 3: register-built MFMA B-fragments, no V LDS round-trip.
// 512 blocks (1/batch row), 512 threads (8 waves).
// Score GEMM H[l][p] = sum_k W1[l][k]*V[k][p]: A=W1 frags from global (resident),
// B built per-lane: V[k][p] = ah[i][k]*ah[j][k] via 2x ds_read_b128 + pk_mul.
// Pass 2 as MFMA: g = M @ ah (M[i][j]=e_ij upper-tri), tmp[k] = sum_i ah[i][k]*g[i][k].

#define BB 512
#define FF 64
#define NPAIRS 2080
#define THREADS 512
#define NTILES 130            // 2080 / 16
#define NEG_BIG -3.402823466e38f

typedef _Float16 half8 __attribute__((ext_vector_type(8)));
typedef float f32x4 __attribute__((ext_vector_type(4)));

__global__ __launch_bounds__(THREADS, 4) void afm_r3_kernel(
    const float* __restrict__ x,     // [512,64]
    const float* __restrict__ Ww,    // [1,64]
    const float* __restrict__ bw,    // [1]
    const float* __restrict__ cross, // [64,64]
    const float* __restrict__ W1,    // [64,64]
    const float* __restrict__ b1,    // [64]
    const float* __restrict__ w2,    // [64]
    const float* __restrict__ Wd1,   // [32,64]
    const float* __restrict__ bd1,   // [32]
    const float* __restrict__ Wd2,   // [21,32]
    const float* __restrict__ bd2,   // [21]
    const float* __restrict__ Wd3,   // [16,21]
    const float* __restrict__ bd3,   // [16]
    const float* __restrict__ Wo,    // [1,16]
    const float* __restrict__ bo,    // [1]
    float* __restrict__ out)         // [512]
{
    __shared__ __align__(16) _Float16 ah_s [FF][72];  // a[i][k] f16, stride 144B (16B-mult)
    __shared__ __align__(16) _Float16 aht_s[FF][72];  // a^T[k][i]
    __shared__ __align__(16) _Float16 M_s  [FF][72];  // e-matrix (upper-tri), f16
    __shared__ float s_s[NPAIRS];                     // scores, then e
    __shared__ unsigned short lut_s[NPAIRS];
    __shared__ float x_sh[FF];
    __shared__ float part_s[4][FF];
    __shared__ float mlp_s[FF];
    __shared__ float red_s[16];
    __shared__ float scal_s[2];

    const int tid  = threadIdx.x;
    const int lane = tid & 63;
    const int wave = tid >> 6;
    const int b    = blockIdx.x;
    const int m    = lane & 15;
    const int q    = lane >> 4;

    // ---- stage x ----
    if (tid < FF) x_sh[tid] = x[b * FF + tid];
    __syncthreads();

    // ---- ah = f16(x_i * cross[i][k]), plus transpose; pair LUT ----
    for (int idx = tid; idx < FF * FF; idx += THREADS) {
        const int i = idx >> 6, k = idx & 63;
        const _Float16 v = (_Float16)(x_sh[i] * cross[idx]);
        ah_s[i][k]  = v;
        aht_s[k][i] = v;
    }
    if (tid < FF) {
        const int i = tid;
        const int basei = i * FF - (i * (i - 1)) / 2;
        const bool xi = (x_sh[i] != 0.f);
        for (int j = i; j < FF; ++j) {
            const int valid = (xi && (x_sh[j] != 0.f)) ? 0x8000 : 0;
            lut_s[basei + (j - i)] = (unsigned short)((i << 8) | j | valid);
        }
    }

    // ---- A-fragments (W1 -> f16) straight from global; b1/w2 to registers ----
    half8 afr[4][2];
    #pragma unroll
    for (int mt = 0; mt < 4; ++mt)
        #pragma unroll
        for (int kt = 0; kt < 2; ++kt) {
            const float* wr = W1 + (mt * 16 + m) * FF + kt * 32 + q * 8;
            half8 h;
            #pragma unroll
            for (int jj = 0; jj < 8; ++jj) h[jj] = (_Float16)wr[jj];
            afr[mt][kt] = h;
        }
    float b1r[16], w2r[16];
    #pragma unroll
    for (int mt = 0; mt < 4; ++mt)
        #pragma unroll
        for (int r = 0; r < 4; ++r) {
            b1r[mt * 4 + r] = b1[mt * 16 + q * 4 + r];
            w2r[mt * 4 + r] = w2[mt * 16 + q * 4 + r];
        }
    __syncthreads();

    // ---- pass 1: scores, barrier-free across waves ----
    for (int nt = wave; nt < NTILES; nt += 8) {
        const int p0 = nt * 16;
        const int ij = lut_s[p0 + m];
        const int i = (ij >> 8) & 63, j = ij & 63;
        const half8 ai0 = *(const half8*)&ah_s[i][q * 8];
        const half8 aj0 = *(const half8*)&ah_s[j][q * 8];
        const half8 ai1 = *(const half8*)&ah_s[i][32 + q * 8];
        const half8 aj1 = *(const half8*)&ah_s[j][32 + q * 8];
        const half8 bf0 = ai0 * aj0;   // V[k][p] fragment, kt=0
        const half8 bf1 = ai1 * aj1;   // kt=1
        float sp = 0.f;
        #pragma unroll
        for (int mt = 0; mt < 4; ++mt) {
            f32x4 acc;
            #pragma unroll
            for (int r = 0; r < 4; ++r) acc[r] = b1r[mt * 4 + r];
            acc = __builtin_amdgcn_mfma_f32_16x16x32_f16(afr[mt][0], bf0, acc, 0, 0, 0);
            acc = __builtin_amdgcn_mfma_f32_16x16x32_f16(afr[mt][1], bf1, acc, 0, 0, 0);
            #pragma unroll
            for (int r = 0; r < 4; ++r)
                sp = fmaf(w2r[mt * 4 + r], fmaxf(acc[r], 0.f), sp);
        }
        sp += __shfl_xor(sp, 16, 64);
        sp += __shfl_xor(sp, 32, 64);
        if (lane < 16) {
            const int p = p0 + lane;
            s_s[p] = (lut_s[p] & 0x8000) ? sp : NEG_BIG;
        }
    }
    __syncthreads();

    // ---- softmax (0-logit seed, as reference) ----
    float mx = 0.0f;
    for (int p = tid; p < NPAIRS; p += THREADS) mx = fmaxf(mx, s_s[p]);
    #pragma unroll
    for (int off = 32; off > 0; off >>= 1)
        mx = fmaxf(mx, __shfl_xor(mx, off, 64));
    if (lane == 0) red_s[wave] = mx;
    __syncthreads();
    if (tid == 0) {
        float mm = red_s[0];
        for (int w = 1; w < 8; ++w) mm = fmaxf(mm, red_s[w]);
        scal_s[0] = mm;
    }
    __syncthreads();
    const float mval = scal_s[0];

    float sum = 0.f;
    for (int p = tid; p < NPAIRS; p += THREADS) {
        const float e = __expf(s_s[p] - mval);   // NEG_BIG -> 0
        s_s[p] = e;
        sum += e;
    }
    #pragma unroll
    for (int off = 32; off > 0; off >>= 1)
        sum += __shfl_xor(sum, off, 64);
    if (lane == 0) red_s[8 + wave] = sum;
    __syncthreads();
    if (tid == 0) {
        float ss = __expf(-mval);
        for (int w = 0; w < 8; ++w) ss += red_s[8 + w];
        scal_s[1] = ss;
    }
    __syncthreads();
    const float denom = scal_s[1];

    // ---- build M[i][j] = e_ij (j>=i) else 0, f16 ----
    for (int idx = tid; idx < FF * FF; idx += THREADS) {
        const int i = idx >> 6, j = idx & 63;
        float e = 0.f;
        if (j >= i) e = s_s[i * FF - (i * (i - 1)) / 2 + (j - i)];
        M_s[i][j] = (_Float16)e;
    }
    __syncthreads();

    // ---- pass 2 as MFMA: g = M @ ah; tmp[k] = sum_i ah[i][k] * g[i][k] ----
    {
        const int t0 = wave * 2;
        #pragma unroll
        for (int t = t0; t < t0 + 2; ++t) {
            const int i0 = (t >> 2) * 16, k0 = (t & 3) * 16;
            const half8 a0  = *(const half8*)&M_s[i0 + m][q * 8];
            const half8 a1  = *(const half8*)&M_s[i0 + m][32 + q * 8];
            const half8 bb0 = *(const half8*)&aht_s[k0 + m][q * 8];
            const half8 bb1 = *(const half8*)&aht_s[k0 + m][32 + q * 8];
            f32x4 g = {0.f, 0.f, 0.f, 0.f};
            g = __builtin_amdgcn_mfma_f32_16x16x32_f16(a0, bb0, g, 0, 0, 0);
            g = __builtin_amdgcn_mfma_f32_16x16x32_f16(a1, bb1, g, 0, 0, 0);
            // C row = i0+q*4+r, col = k0+m; multiply by ah[i][k] and reduce over i
            const _Float16* ap = &aht_s[k0 + m][i0 + q * 4];
            float s4 = (float)ap[0] * g[0] + (float)ap[1] * g[1]
                     + (float)ap[2] * g[2] + (float)ap[3] * g[3];
            s4 += __shfl_xor(s4, 16, 64);
            s4 += __shfl_xor(s4, 32, 64);
            if (lane < 16) part_s[i0 >> 4][k0 + lane] = s4;
        }
    }
    __syncthreads();
    if (tid < FF)
        mlp_s[tid] = (part_s[0][tid] + part_s[1][tid] +
                      part_s[2][tid] + part_s[3][tid]) / denom;
    __syncthreads();

    // ---- deep MLP: 64 -> 32 -> 21 -> 16 -> 1 ----
    float hv = 0.f;
    if (tid < 32) {
        float a1v = bd1[tid];
        for (int k = 0; k < 64; ++k) a1v = fmaf(Wd1[tid * 64 + k], mlp_s[k], a1v);
        hv = fmaxf(a1v, 0.f);
    }
    __syncthreads();
    if (tid < 32) mlp_s[tid] = hv;
    __syncthreads();
    if (tid < 21) {
        float a2 = bd2[tid];
        for (int k = 0; k < 32; ++k) a2 = fmaf(Wd2[tid * 32 + k], mlp_s[k], a2);
        hv = fmaxf(a2, 0.f);
    }
    __syncthreads();
    if (tid < 21) mlp_s[tid] = hv;
    __syncthreads();
    if (tid < 16) {
        float a3 = bd3[tid];
        for (int k = 0; k < 21; ++k) a3 = fmaf(Wd3[tid * 21 + k], mlp_s[k], a3);
        hv = fmaxf(a3, 0.f);
    }
    __syncthreads();
    if (tid < 16) mlp_s[tid] = hv;
    __syncthreads();

    if (tid == 0) {
        float deep = bo[0];
        for (int k = 0; k < 16; ++k) deep = fmaf(Wo[k], mlp_s[k], deep);
        float lin = bw[0];
        for (int k = 0; k < 64; ++k) lin = fmaf(Ww[k], x_sh[k], lin);
        const float z = lin + deep;
        out[b] = 1.f / (1.f + __expf(-z));
    }
}

extern "C" void kernel_launch(void* const* d_in, const int* in_sizes, int n_in,
                              void* d_out, int out_size, void* d_ws, size_t ws_size,
                              hipStream_t stream) {
    const float* xp    = (const float*)d_in[0];
    const float* Ww    = (const float*)d_in[1];
    const float* bw    = (const float*)d_in[2];
    const float* cross = (const float*)d_in[3];
    const float* W1    = (const float*)d_in[4];
    const float* b1    = (const float*)d_in[5];
    const float* w2    = (const float*)d_in[6];
    const float* Wd1   = (const float*)d_in[7];
    const float* bd1   = (const float*)d_in[8];
    const float* Wd2   = (const float*)d_in[9];
    const float* bd2   = (const float*)d_in[10];
    const float* Wd3   = (const float*)d_in[11];
    const float* bd3   = (const float*)d_in[12];
    const float* Wo    = (const float*)d_in[13];
    const float* bo    = (const float*)d_in[14];
    float* outp = (float*)d_out;

    afm_r3_kernel<<<BB, THREADS, 0, stream>>>(xp, Ww, bw, cross, W1, b1, w2,
                                              Wd1, bd1, Wd2, bd2, Wd3, bd3,
                                              Wo, bo, outp);
}

// Round 4
// 103.397 us; speedup vs baseline: 8.9459x; 1.0088x over previous
//
#include <hip/hip_runtime.h>
#include <math.h>

// AFM forward, round 4: 2-tile pipelined pass-1, fused exp/M/sum pass,
// fewer barriers. 512 blocks (1/batch row), 512 threads (8 waves).
// Score GEMM H[l][p] = sum_k W1[l][k]*V[k][p] via mfma_f32_16x16x32_f16,
// B-fragments built in registers from LDS ah rows (no V round-trip).
// Pass 2 as MFMA: g = M @ ah (M[i][j]=e_ij upper-tri), tmp[k]=sum_i ah[i][k]*g[i][k].

#define BB 512
#define FF 64
#define NPAIRS 2080
#define THREADS 512
#define NIT2 65               // 130 16-pair tiles processed 2 at a time
#define NEG_BIG -3.402823466e38f

typedef _Float16 half8 __attribute__((ext_vector_type(8)));
typedef float f32x4 __attribute__((ext_vector_type(4)));

__global__ __launch_bounds__(THREADS, 4) void afm_r4_kernel(
    const float* __restrict__ x,     // [512,64]
    const float* __restrict__ Ww,    // [1,64]
    const float* __restrict__ bw,    // [1]
    const float* __restrict__ cross, // [64,64]
    const float* __restrict__ W1,    // [64,64]
    const float* __restrict__ b1,    // [64]
    const float* __restrict__ w2,    // [64]
    const float* __restrict__ Wd1,   // [32,64]
    const float* __restrict__ bd1,   // [32]
    const float* __restrict__ Wd2,   // [21,32]
    const float* __restrict__ bd2,   // [21]
    const float* __restrict__ Wd3,   // [16,21]
    const float* __restrict__ bd3,   // [16]
    const float* __restrict__ Wo,    // [1,16]
    const float* __restrict__ bo,    // [1]
    float* __restrict__ out)         // [512]
{
    __shared__ __align__(16) _Float16 ah_s [FF][72];  // a[i][k] f16
    __shared__ __align__(16) _Float16 aht_s[FF][72];  // a^T[k][i]
    __shared__ __align__(16) _Float16 M_s  [FF][72];  // e-matrix (upper-tri), f16
    __shared__ float s_s[NPAIRS];
    __shared__ unsigned short lut_s[NPAIRS];
    __shared__ float x_sh[FF];
    __shared__ float part_s[4][FF];
    __shared__ float mlp_s[FF];
    __shared__ float red_s[16];

    const int tid  = threadIdx.x;
    const int lane = tid & 63;
    const int wave = tid >> 6;
    const int b    = blockIdx.x;
    const int m    = lane & 15;
    const int q    = lane >> 4;

    // ---- stage x ----
    if (tid < FF) x_sh[tid] = x[b * FF + tid];
    __syncthreads();

    // ---- ah/aht (f16), M zero, pair LUT (with valid bit 15) ----
    for (int idx = tid; idx < FF * FF; idx += THREADS) {
        const int i = idx >> 6, k = idx & 63;
        const _Float16 v = (_Float16)(x_sh[i] * cross[idx]);
        ah_s[i][k]  = v;
        aht_s[k][i] = v;
    }
    for (int idx = tid; idx < (FF * 72) / 2; idx += THREADS)
        ((int*)M_s)[idx] = 0;
    if (tid < FF) {
        const int i = tid;
        const int basei = i * FF - (i * (i - 1)) / 2;
        const bool xi = (x_sh[i] != 0.f);
        for (int j = i; j < FF; ++j) {
            const int valid = (xi && (x_sh[j] != 0.f)) ? 0x8000 : 0;
            lut_s[basei + (j - i)] = (unsigned short)((i << 8) | j | valid);
        }
    }

    // ---- A-fragments (W1->f16) from global; b1/w2 resident ----
    half8 afr[4][2];
    #pragma unroll
    for (int mt = 0; mt < 4; ++mt)
        #pragma unroll
        for (int kt = 0; kt < 2; ++kt) {
            const float* wr = W1 + (mt * 16 + m) * FF + kt * 32 + q * 8;
            half8 h;
            #pragma unroll
            for (int jj = 0; jj < 8; ++jj) h[jj] = (_Float16)wr[jj];
            afr[mt][kt] = h;
        }
    float b1r[16], w2r[16];
    #pragma unroll
    for (int mt = 0; mt < 4; ++mt)
        #pragma unroll
        for (int r = 0; r < 4; ++r) {
            b1r[mt * 4 + r] = b1[mt * 16 + q * 4 + r];
            w2r[mt * 4 + r] = w2[mt * 16 + q * 4 + r];
        }
    __syncthreads();

    // ---- pass 1: scores, 2 tiles (32 pairs) per iteration ----
    for (int it = wave; it < NIT2; it += 8) {
        const int p0 = it * 32;
        const int ijA = lut_s[p0 + m];
        const int ijB = lut_s[p0 + 16 + m];
        const int iA = (ijA >> 8) & 63, jA = ijA & 63;
        const int iB = (ijB >> 8) & 63, jB = ijB & 63;
        const half8 bA0 = (*(const half8*)&ah_s[iA][q * 8])      * (*(const half8*)&ah_s[jA][q * 8]);
        const half8 bA1 = (*(const half8*)&ah_s[iA][32 + q * 8]) * (*(const half8*)&ah_s[jA][32 + q * 8]);
        const half8 bB0 = (*(const half8*)&ah_s[iB][q * 8])      * (*(const half8*)&ah_s[jB][q * 8]);
        const half8 bB1 = (*(const half8*)&ah_s[iB][32 + q * 8]) * (*(const half8*)&ah_s[jB][32 + q * 8]);
        float spA = 0.f, spB = 0.f;
        #pragma unroll
        for (int mt = 0; mt < 4; ++mt) {
            f32x4 aA, aB;
            #pragma unroll
            for (int r = 0; r < 4; ++r) { aA[r] = b1r[mt * 4 + r]; aB[r] = b1r[mt * 4 + r]; }
            aA = __builtin_amdgcn_mfma_f32_16x16x32_f16(afr[mt][0], bA0, aA, 0, 0, 0);
            aB = __builtin_amdgcn_mfma_f32_16x16x32_f16(afr[mt][0], bB0, aB, 0, 0, 0);
            aA = __builtin_amdgcn_mfma_f32_16x16x32_f16(afr[mt][1], bA1, aA, 0, 0, 0);
            aB = __builtin_amdgcn_mfma_f32_16x16x32_f16(afr[mt][1], bB1, aB, 0, 0, 0);
            #pragma unroll
            for (int r = 0; r < 4; ++r) {
                spA = fmaf(w2r[mt * 4 + r], fmaxf(aA[r], 0.f), spA);
                spB = fmaf(w2r[mt * 4 + r], fmaxf(aB[r], 0.f), spB);
            }
        }
        spA += __shfl_xor(spA, 16, 64);
        spA += __shfl_xor(spA, 32, 64);
        spB += __shfl_xor(spB, 16, 64);
        spB += __shfl_xor(spB, 32, 64);
        if (lane < 16) {
            s_s[p0 + lane]      = (ijA & 0x8000) ? spA : NEG_BIG;
            s_s[p0 + 16 + lane] = (ijB & 0x8000) ? spB : NEG_BIG;
        }
    }
    __syncthreads();

    // ---- softmax max (0-seeded) ----
    float mx = 0.0f;
    for (int p = tid; p < NPAIRS; p += THREADS) mx = fmaxf(mx, s_s[p]);
    #pragma unroll
    for (int off = 32; off > 0; off >>= 1)
        mx = fmaxf(mx, __shfl_xor(mx, off, 64));
    if (lane == 0) red_s[wave] = mx;
    __syncthreads();
    float mval = red_s[0];
    #pragma unroll
    for (int w = 1; w < 8; ++w) mval = fmaxf(mval, red_s[w]);

    // ---- fused: e = exp(s-m), M[i][j] = e, sum e ----
    float sum = 0.f;
    for (int p = tid; p < NPAIRS; p += THREADS) {
        const int ij = lut_s[p];
        const float e = __expf(s_s[p] - mval);   // NEG_BIG -> 0
        sum += e;
        M_s[(ij >> 8) & 63][ij & 63] = (_Float16)e;
    }
    #pragma unroll
    for (int off = 32; off > 0; off >>= 1)
        sum += __shfl_xor(sum, off, 64);
    if (lane == 0) red_s[8 + wave] = sum;
    __syncthreads();
    float denom = __expf(-mval);
    #pragma unroll
    for (int w = 0; w < 8; ++w) denom += red_s[8 + w];

    // ---- pass 2 as MFMA: g = M @ ah; tmp[k] = sum_i ah[i][k]*g[i][k] ----
    {
        const int t0 = wave * 2;
        #pragma unroll
        for (int t = t0; t < t0 + 2; ++t) {
            const int i0 = (t >> 2) * 16, k0 = (t & 3) * 16;
            const half8 a0  = *(const half8*)&M_s[i0 + m][q * 8];
            const half8 a1  = *(const half8*)&M_s[i0 + m][32 + q * 8];
            const half8 bb0 = *(const half8*)&aht_s[k0 + m][q * 8];
            const half8 bb1 = *(const half8*)&aht_s[k0 + m][32 + q * 8];
            f32x4 g = {0.f, 0.f, 0.f, 0.f};
            g = __builtin_amdgcn_mfma_f32_16x16x32_f16(a0, bb0, g, 0, 0, 0);
            g = __builtin_amdgcn_mfma_f32_16x16x32_f16(a1, bb1, g, 0, 0, 0);
            const _Float16* ap = &aht_s[k0 + m][i0 + q * 4];
            float s4 = (float)ap[0] * g[0] + (float)ap[1] * g[1]
                     + (float)ap[2] * g[2] + (float)ap[3] * g[3];
            s4 += __shfl_xor(s4, 16, 64);
            s4 += __shfl_xor(s4, 32, 64);
            if (lane < 16) part_s[i0 >> 4][k0 + lane] = s4;
        }
    }
    __syncthreads();
    if (tid < FF)
        mlp_s[tid] = (part_s[0][tid] + part_s[1][tid] +
                      part_s[2][tid] + part_s[3][tid]) / denom;
    __syncthreads();

    // ---- deep MLP: 64 -> 32 -> 21 -> 16 -> 1 ----
    float hv = 0.f;
    if (tid < 32) {
        float a1v = bd1[tid];
        for (int k = 0; k < 64; ++k) a1v = fmaf(Wd1[tid * 64 + k], mlp_s[k], a1v);
        hv = fmaxf(a1v, 0.f);
    }
    __syncthreads();
    if (tid < 32) mlp_s[tid] = hv;
    __syncthreads();
    if (tid < 21) {
        float a2 = bd2[tid];
        for (int k = 0; k < 32; ++k) a2 = fmaf(Wd2[tid * 32 + k], mlp_s[k], a2);
        hv = fmaxf(a2, 0.f);
    }
    __syncthreads();
    if (tid < 21) mlp_s[tid] = hv;
    __syncthreads();
    if (tid < 16) {
        float a3 = bd3[tid];
        for (int k = 0; k < 21; ++k) a3 = fmaf(Wd3[tid * 21 + k], mlp_s[k], a3);
        hv = fmaxf(a3, 0.f);
    }
    __syncthreads();
    if (tid < 16) mlp_s[tid] = hv;
    __syncthreads();

    if (tid == 0) {
        float deep = bo[0];
        for (int k = 0; k < 16; ++k) deep = fmaf(Wo[k], mlp_s[k], deep);
        float lin = bw[0];
        for (int k = 0; k < 64; ++k) lin = fmaf(Ww[k], x_sh[k], lin);
        const float z = lin + deep;
        out[b] = 1.f / (1.f + __expf(-z));
    }
}

extern "C" void kernel_launch(void* const* d_in, const int* in_sizes, int n_in,
                              void* d_out, int out_size, void* d_ws, size_t ws_size,
                              hipStream_t stream) {
    const float* xp    = (const float*)d_in[0];
    const float* Ww    = (const float*)d_in[1];
    const float* bw    = (const float*)d_in[2];
    const float* cross = (const float*)d_in[3];
    const float* W1    = (const float*)d_in[4];
    const float* b1    = (const float*)d_in[5];
    const float* w2    = (const float*)d_in[6];
    const float* Wd1   = (const float*)d_in[7];
    const float* bd1   = (const float*)d_in[8];
    const float* Wd2   = (const float*)d_in[9];
    const float* bd2   = (const float*)d_in[10];
    const float* Wd3   = (const float*)d_in[11];
    const float* bd3   = (const float*)d_in[12];
    const float* Wo    = (const float*)d_in[13];
    const float* bo    = (const float*)d_in[14];
    float* outp = (float*)d_out;

    afm_r4_kernel<<<BB, THREADS, 0, stream>>>(xp, Ww, bw, cross, W1, b1, w2,
                                              Wd1, bd1, Wd2, bd2, Wd3, bd3,
                                              Wo, bo, outp);
}

// Round 5
// 103.266 us; speedup vs baseline: 8.9572x; 1.0013x over previous
//
#include <hip/hip_runtime.h>
#include <math.h>

// AFM forward, round 5: r4 structure with conflict-breaking LDS row stride.
// Row stride = 68 halves (34 dwords, gcd(34,32)=2): strided-row reads are
// <=4-way bank-aliased (1.58x) instead of 8-way (2.94x) at stride 72 (16B mult).
// Rows are 8B-aligned -> all row-fragment LDS loads are b64 pairs, not b128.

#define BB 512
#define FF 64
#define STR 68                // halves per row: 136B, 34 dwords
#define NPAIRS 2080
#define THREADS 512
#define NIT2 65               // 130 16-pair tiles, 2 per iteration
#define NEG_BIG -3.402823466e38f

typedef _Float16 half8 __attribute__((ext_vector_type(8)));
typedef _Float16 half4 __attribute__((ext_vector_type(4)));
typedef float f32x4 __attribute__((ext_vector_type(4)));

// 16B row-fragment load from an 8B-aligned row: two ds_read_b64.
__device__ __forceinline__ half8 ld8(const _Float16* p) {
    half8 v;
    *(half4*)&v       = *(const half4*)p;
    *((half4*)&v + 1) = *(const half4*)(p + 4);
    return v;
}

__global__ __launch_bounds__(THREADS, 4) void afm_r5_kernel(
    const float* __restrict__ x,     // [512,64]
    const float* __restrict__ Ww,    // [1,64]
    const float* __restrict__ bw,    // [1]
    const float* __restrict__ cross, // [64,64]
    const float* __restrict__ W1,    // [64,64]
    const float* __restrict__ b1,    // [64]
    const float* __restrict__ w2,    // [64]
    const float* __restrict__ Wd1,   // [32,64]
    const float* __restrict__ bd1,   // [32]
    const float* __restrict__ Wd2,   // [21,32]
    const float* __restrict__ bd2,   // [21]
    const float* __restrict__ Wd3,   // [16,21]
    const float* __restrict__ bd3,   // [16]
    const float* __restrict__ Wo,    // [1,16]
    const float* __restrict__ bo,    // [1]
    float* __restrict__ out)         // [512]
{
    __shared__ __align__(16) _Float16 ah_s [FF * STR];  // a[i][k] f16
    __shared__ __align__(16) _Float16 aht_s[FF * STR];  // a^T[k][i]
    __shared__ __align__(16) _Float16 M_s  [FF * STR];  // e-matrix (upper-tri)
    __shared__ float s_s[NPAIRS];
    __shared__ unsigned short lut_s[NPAIRS];
    __shared__ float x_sh[FF];
    __shared__ float part_s[4][FF];
    __shared__ float mlp_s[FF];
    __shared__ float red_s[16];

    const int tid  = threadIdx.x;
    const int lane = tid & 63;
    const int wave = tid >> 6;
    const int b    = blockIdx.x;
    const int m    = lane & 15;
    const int q    = lane >> 4;

    // ---- stage x ----
    if (tid < FF) x_sh[tid] = x[b * FF + tid];
    __syncthreads();

    // ---- ah/aht (f16), M zero, pair LUT (valid bit 15) ----
    for (int idx = tid; idx < FF * FF; idx += THREADS) {
        const int i = idx >> 6, k = idx & 63;
        const _Float16 v = (_Float16)(x_sh[i] * cross[idx]);
        ah_s[i * STR + k]  = v;
        aht_s[k * STR + i] = v;
    }
    for (int idx = tid; idx < (FF * STR) / 2; idx += THREADS)
        ((int*)M_s)[idx] = 0;
    if (tid < FF) {
        const int i = tid;
        const int basei = i * FF - (i * (i - 1)) / 2;
        const bool xi = (x_sh[i] != 0.f);
        for (int j = i; j < FF; ++j) {
            const int valid = (xi && (x_sh[j] != 0.f)) ? 0x8000 : 0;
            lut_s[basei + (j - i)] = (unsigned short)((i << 8) | j | valid);
        }
    }

    // ---- A-fragments (W1->f16) from global (L1 broadcast); b1/w2 resident ----
    half8 afr[4][2];
    #pragma unroll
    for (int mt = 0; mt < 4; ++mt)
        #pragma unroll
        for (int kt = 0; kt < 2; ++kt) {
            const float* wr = W1 + (mt * 16 + m) * FF + kt * 32 + q * 8;
            half8 h;
            #pragma unroll
            for (int jj = 0; jj < 8; ++jj) h[jj] = (_Float16)wr[jj];
            afr[mt][kt] = h;
        }
    float b1r[16], w2r[16];
    #pragma unroll
    for (int mt = 0; mt < 4; ++mt)
        #pragma unroll
        for (int r = 0; r < 4; ++r) {
            b1r[mt * 4 + r] = b1[mt * 16 + q * 4 + r];
            w2r[mt * 4 + r] = w2[mt * 16 + q * 4 + r];
        }
    __syncthreads();

    // ---- pass 1: scores, 2 tiles (32 pairs) per iteration ----
    for (int it = wave; it < NIT2; it += 8) {
        const int p0 = it * 32;
        const int ijA = lut_s[p0 + m];
        const int ijB = lut_s[p0 + 16 + m];
        const int iA = (ijA >> 8) & 63, jA = ijA & 63;
        const int iB = (ijB >> 8) & 63, jB = ijB & 63;
        const half8 bA0 = ld8(&ah_s[iA * STR + q * 8])      * ld8(&ah_s[jA * STR + q * 8]);
        const half8 bA1 = ld8(&ah_s[iA * STR + 32 + q * 8]) * ld8(&ah_s[jA * STR + 32 + q * 8]);
        const half8 bB0 = ld8(&ah_s[iB * STR + q * 8])      * ld8(&ah_s[jB * STR + q * 8]);
        const half8 bB1 = ld8(&ah_s[iB * STR + 32 + q * 8]) * ld8(&ah_s[jB * STR + 32 + q * 8]);
        float spA = 0.f, spB = 0.f;
        #pragma unroll
        for (int mt = 0; mt < 4; ++mt) {
            f32x4 aA, aB;
            #pragma unroll
            for (int r = 0; r < 4; ++r) { aA[r] = b1r[mt * 4 + r]; aB[r] = b1r[mt * 4 + r]; }
            aA = __builtin_amdgcn_mfma_f32_16x16x32_f16(afr[mt][0], bA0, aA, 0, 0, 0);
            aB = __builtin_amdgcn_mfma_f32_16x16x32_f16(afr[mt][0], bB0, aB, 0, 0, 0);
            aA = __builtin_amdgcn_mfma_f32_16x16x32_f16(afr[mt][1], bA1, aA, 0, 0, 0);
            aB = __builtin_amdgcn_mfma_f32_16x16x32_f16(afr[mt][1], bB1, aB, 0, 0, 0);
            #pragma unroll
            for (int r = 0; r < 4; ++r) {
                spA = fmaf(w2r[mt * 4 + r], fmaxf(aA[r], 0.f), spA);
                spB = fmaf(w2r[mt * 4 + r], fmaxf(aB[r], 0.f), spB);
            }
        }
        spA += __shfl_xor(spA, 16, 64);
        spA += __shfl_xor(spA, 32, 64);
        spB += __shfl_xor(spB, 16, 64);
        spB += __shfl_xor(spB, 32, 64);
        if (lane < 16) {
            s_s[p0 + lane]      = (ijA & 0x8000) ? spA : NEG_BIG;
            s_s[p0 + 16 + lane] = (ijB & 0x8000) ? spB : NEG_BIG;
        }
    }
    __syncthreads();

    // ---- softmax max (0-seeded) ----
    float mx = 0.0f;
    for (int p = tid; p < NPAIRS; p += THREADS) mx = fmaxf(mx, s_s[p]);
    #pragma unroll
    for (int off = 32; off > 0; off >>= 1)
        mx = fmaxf(mx, __shfl_xor(mx, off, 64));
    if (lane == 0) red_s[wave] = mx;
    __syncthreads();
    float mval = red_s[0];
    #pragma unroll
    for (int w = 1; w < 8; ++w) mval = fmaxf(mval, red_s[w]);

    // ---- fused: e = exp(s-m), M[i][j] = e, sum e ----
    float sum = 0.f;
    for (int p = tid; p < NPAIRS; p += THREADS) {
        const int ij = lut_s[p];
        const float e = __expf(s_s[p] - mval);   // NEG_BIG -> 0
        sum += e;
        M_s[((ij >> 8) & 63) * STR + (ij & 63)] = (_Float16)e;
    }
    #pragma unroll
    for (int off = 32; off > 0; off >>= 1)
        sum += __shfl_xor(sum, off, 64);
    if (lane == 0) red_s[8 + wave] = sum;
    __syncthreads();
    float denom = __expf(-mval);
    #pragma unroll
    for (int w = 0; w < 8; ++w) denom += red_s[8 + w];

    // ---- pass 2 as MFMA: g = M @ ah; tmp[k] = sum_i ah[i][k]*g[i][k] ----
    {
        const int t0 = wave * 2;
        #pragma unroll
        for (int t = t0; t < t0 + 2; ++t) {
            const int i0 = (t >> 2) * 16, k0 = (t & 3) * 16;
            const half8 a0  = ld8(&M_s[(i0 + m) * STR + q * 8]);
            const half8 a1  = ld8(&M_s[(i0 + m) * STR + 32 + q * 8]);
            const half8 bb0 = ld8(&aht_s[(k0 + m) * STR + q * 8]);
            const half8 bb1 = ld8(&aht_s[(k0 + m) * STR + 32 + q * 8]);
            f32x4 g = {0.f, 0.f, 0.f, 0.f};
            g = __builtin_amdgcn_mfma_f32_16x16x32_f16(a0, bb0, g, 0, 0, 0);
            g = __builtin_amdgcn_mfma_f32_16x16x32_f16(a1, bb1, g, 0, 0, 0);
            const half4 ap = *(const half4*)&aht_s[(k0 + m) * STR + i0 + q * 4];
            float s4 = (float)ap[0] * g[0] + (float)ap[1] * g[1]
                     + (float)ap[2] * g[2] + (float)ap[3] * g[3];
            s4 += __shfl_xor(s4, 16, 64);
            s4 += __shfl_xor(s4, 32, 64);
            if (lane < 16) part_s[i0 >> 4][k0 + lane] = s4;
        }
    }
    __syncthreads();
    if (tid < FF)
        mlp_s[tid] = (part_s[0][tid] + part_s[1][tid] +
                      part_s[2][tid] + part_s[3][tid]) / denom;
    __syncthreads();

    // ---- deep MLP: 64 -> 32 -> 21 -> 16 -> 1 ----
    float hv = 0.f;
    if (tid < 32) {
        float a1v = bd1[tid];
        for (int k = 0; k < 64; ++k) a1v = fmaf(Wd1[tid * 64 + k], mlp_s[k], a1v);
        hv = fmaxf(a1v, 0.f);
    }
    __syncthreads();
    if (tid < 32) mlp_s[tid] = hv;
    __syncthreads();
    if (tid < 21) {
        float a2 = bd2[tid];
        for (int k = 0; k < 32; ++k) a2 = fmaf(Wd2[tid * 32 + k], mlp_s[k], a2);
        hv = fmaxf(a2, 0.f);
    }
    __syncthreads();
    if (tid < 21) mlp_s[tid] = hv;
    __syncthreads();
    if (tid < 16) {
        float a3 = bd3[tid];
        for (int k = 0; k < 21; ++k) a3 = fmaf(Wd3[tid * 21 + k], mlp_s[k], a3);
        hv = fmaxf(a3, 0.f);
    }
    __syncthreads();
    if (tid < 16) mlp_s[tid] = hv;
    __syncthreads();

    if (tid == 0) {
        float deep = bo[0];
        for (int k = 0; k < 16; ++k) deep = fmaf(Wo[k], mlp_s[k], deep);
        float lin = bw[0];
        for (int k = 0; k < 64; ++k) lin = fmaf(Ww[k], x_sh[k], lin);
        const float z = lin + deep;
        out[b] = 1.f / (1.f + __expf(-z));
    }
}

extern "C" void kernel_launch(void* const* d_in, const int* in_sizes, int n_in,
                              void* d_out, int out_size, void* d_ws, size_t ws_size,
                              hipStream_t stream) {
    const float* xp    = (const float*)d_in[0];
    const float* Ww    = (const float*)d_in[1];
    const float* bw    = (const float*)d_in[2];
    const float* cross = (const float*)d_in[3];
    const float* W1    = (const float*)d_in[4];
    const float* b1    = (const float*)d_in[5];
    const float* w2    = (const float*)d_in[6];
    const float* Wd1   = (const float*)d_in[7];
    const float* bd1   = (const float*)d_in[8];
    const float* Wd2   = (const float*)d_in[9];
    const float* bd2   = (const float*)d_in[10];
    const float* Wd3   = (const float*)d_in[11];
    const float* bd3   = (const float*)d_in[12];
    const float* Wo    = (const float*)d_in[13];
    const float* bo    = (const float*)d_in[14];
    float* outp = (float*)d_out;

    afm_r5_kernel<<<BB, THREADS, 0, stream>>>(xp, Ww, bw, cross, W1, b1, w2,
                                              Wd1, bd1, Wd2, bd2, Wd3, bd3,
                                              Wo, bo, outp);
}